// Round 3
// baseline (101.797 us; speedup 1.0000x reference)
//
#include <hip/hip_runtime.h>
#include <hip/hip_bf16.h>

// out[b,n] = 2*x.y - ||x_b||^2 - ||y_n||^2
// x: [M=4096, K=1024] f32   y: [N=8192, K=1024] f32   out: [M, N] f32
//
// Round 3: 256x256 bf16 MFMA GEMM, 4 quadrant-phases per K-tile.
// - A-half / B-quarter fragments read ONCE per tile, carried in regs
//   (24 ds_read_b128/wave/tile instead of 32)
// - all 8 next-tile global_load_lds issued at phase 0, vmcnt(0) at phase 3
//   (~3 phases of latency cover; loads in flight across 6 barriers)
// - T1 XCD swizzle, T2 LDS XOR swizzle (pre-swizzled global source,
//   swizzled ds_read), T5 setprio around MFMA clusters.

typedef __attribute__((ext_vector_type(8))) short bf16x8;
typedef __attribute__((ext_vector_type(4))) float f32x4;

#define BM 256
#define BN 256
#define BK 64
#define KDIM 1024
#define NT (KDIM / BK)   // 16 K-tiles

__device__ __forceinline__ short f2bf(float f) {
    __hip_bfloat16 h = __float2bfloat16(f);
    return *reinterpret_cast<short*>(&h);
}

__device__ __forceinline__ void gld16(const short* g, const short* l) {
    __builtin_amdgcn_global_load_lds(
        (const __attribute__((address_space(1))) unsigned int*)g,
        (__attribute__((address_space(3))) unsigned int*)l,
        16, 0, 0);
}

#define BAR() asm volatile("s_barrier" ::: "memory")

// ---------------- prep: f32 -> bf16 + row squared-norms -------------------
__global__ __launch_bounds__(256) void prep_kernel(
    const float* __restrict__ x, const float* __restrict__ y,
    short* __restrict__ xb, short* __restrict__ yb,
    float* __restrict__ xsq, float* __restrict__ ysq, int M, int N)
{
    int row = blockIdx.x;
    const float* src;
    short* dst;
    float* nrm;
    if (row < M) {
        src = x + (size_t)row * KDIM;
        dst = xb + (size_t)row * KDIM;
        nrm = xsq + row;
    } else {
        int r = row - M;
        src = y + (size_t)r * KDIM;
        dst = yb + (size_t)r * KDIM;
        nrm = ysq + r;
    }
    int t = threadIdx.x;                       // 256 threads, 4 floats each
    float4 v = ((const float4*)src)[t];
    float s = v.x * v.x + v.y * v.y + v.z * v.z + v.w * v.w;
    short4 o;
    o.x = f2bf(v.x); o.y = f2bf(v.y); o.z = f2bf(v.z); o.w = f2bf(v.w);
    ((short4*)dst)[t] = o;

    #pragma unroll
    for (int off = 32; off > 0; off >>= 1) s += __shfl_down(s, off, 64);
    __shared__ float red[4];
    if ((t & 63) == 0) red[t >> 6] = s;
    __syncthreads();
    if (t == 0) *nrm = red[0] + red[1] + red[2] + red[3];
}

// ---------------- main 256x256 phased bf16 MFMA GEMM ----------------------
__global__ __launch_bounds__(512, 2) void gemm_l2(
    const short* __restrict__ xb, const short* __restrict__ yb,
    const float* __restrict__ xsq, const float* __restrict__ ysq,
    float* __restrict__ out, int M, int N)
{
    __shared__ __align__(16) short As[2][BM * BK];   // 64 KiB
    __shared__ __align__(16) short Bs[2][BN * BK];   // 64 KiB

    const int nwg = gridDim.x;          // 512 (divisible by 8)
    const int ntn = N / BN;             // 32
    const int bid = blockIdx.x;
    const int cpx = nwg >> 3;
    const int swz = (bid & 7) * cpx + (bid >> 3);   // bijective XCD swizzle
    const int tm = swz / ntn;
    const int tn = swz % ntn;

    const int tid  = threadIdx.x;       // 512 threads = 8 waves
    const int wid  = tid >> 6;
    const int lane = tid & 63;
    const int wm   = wid >> 2;          // 0..1  (wave tile: 128 x 64)
    const int wn   = wid & 3;           // 0..3
    const int l15  = lane & 15;
    const int hi   = lane >> 4;         // 0..3
    const int s8   = lane & 7;          // swizzle key (== frag row & 7)

    // ---- staging descriptors (identical to round 2, verified) ----
    // LDS dest is LINEAR (gld_lds writes base + lane*16B); the XOR swizzle
    // is applied by permuting the GLOBAL source 16B-block per lane.
    const int srow = wid * 8 + (lane >> 3);          // row within 64-row chunk
    const int scb  = lane & 7;                       // physical 16B block
    const int cbs  = scb ^ ((lane >> 3) & 7);        // swizzled source block
    const short* aG[4];
    const short* bG[4];
    int lofs[4];
    #pragma unroll
    for (int l = 0; l < 4; ++l) {
        int row = l * 64 + srow;
        aG[l] = xb + (size_t)(tm * BM + row) * KDIM + cbs * 8;
        bG[l] = yb + (size_t)(tn * BN + row) * KDIM + cbs * 8;
        lofs[l] = row * BK + scb * 8;                // chunk base + lane*8
    }

    // ---- fragment LDS base offsets (shorts), swizzle applied on read ----
    int abase[8], bbase[4];
    #pragma unroll
    for (int m = 0; m < 8; ++m) abase[m] = (wm * 128 + m * 16 + l15) * BK;
    #pragma unroll
    for (int n = 0; n < 4; ++n) bbase[n] = (wn * 64 + n * 16 + l15) * BK;
    // swizzled k-block byte offset for (ks, hi) read
    const int bo0 = (((0 << 2) | hi) ^ s8) << 3;     // ks = 0
    const int bo1 = (((1 << 2) | hi) ^ s8) << 3;     // ks = 1

    f32x4 acc[8][4] = {};

    // ---- prologue: stage tile 0 into buffer 0 (8 loads/wave) ----
    #pragma unroll
    for (int c = 0; c < 4; ++c) {
        gld16(aG[c], &As[0][lofs[c]]);
        gld16(bG[c], &Bs[0][lofs[c]]);
    }
    asm volatile("s_waitcnt vmcnt(0)" ::: "memory");
    BAR();

    for (int t = 0; t < NT; ++t) {
        const int cur = t & 1;
        const int nxt = cur ^ 1;
        const bool pre = (t + 1 < NT);
        const size_t ko = (size_t)(t + 1) * BK;

        bf16x8 aA[2][4];       // current A-half fragments (ks, m)
        bf16x8 bQ0[2][2];      // B quadrant 0 (n = 0,1), live whole tile
        bf16x8 bQ1[2][2];      // B quadrant 1 (n = 2,3)

        // ===== phase 0: (mh=0, nq=0) — reads 12, issues all 8 prefetch =====
        #pragma unroll
        for (int i = 0; i < 4; ++i) {
            aA[0][i] = *(const bf16x8*)&As[cur][abase[i] + bo0];
            aA[1][i] = *(const bf16x8*)&As[cur][abase[i] + bo1];
        }
        #pragma unroll
        for (int j = 0; j < 2; ++j) {
            bQ0[0][j] = *(const bf16x8*)&Bs[cur][bbase[j] + bo0];
            bQ0[1][j] = *(const bf16x8*)&Bs[cur][bbase[j] + bo1];
        }
        if (pre) {
            #pragma unroll
            for (int c = 0; c < 4; ++c) {
                gld16(aG[c] + ko, &As[nxt][lofs[c]]);
                gld16(bG[c] + ko, &Bs[nxt][lofs[c]]);
            }
        }
        BAR();
        __builtin_amdgcn_s_setprio(1);
        #pragma unroll
        for (int ks = 0; ks < 2; ++ks)
            #pragma unroll
            for (int i = 0; i < 4; ++i)
                #pragma unroll
                for (int j = 0; j < 2; ++j)
                    acc[i][j] = __builtin_amdgcn_mfma_f32_16x16x32_bf16(
                        aA[ks][i], bQ0[ks][j], acc[i][j], 0, 0, 0);
        __builtin_amdgcn_s_setprio(0);
        BAR();

        // ===== phase 1: (mh=0, nq=1) — reads 4 =====
        #pragma unroll
        for (int j = 0; j < 2; ++j) {
            bQ1[0][j] = *(const bf16x8*)&Bs[cur][bbase[2 + j] + bo0];
            bQ1[1][j] = *(const bf16x8*)&Bs[cur][bbase[2 + j] + bo1];
        }
        BAR();
        __builtin_amdgcn_s_setprio(1);
        #pragma unroll
        for (int ks = 0; ks < 2; ++ks)
            #pragma unroll
            for (int i = 0; i < 4; ++i)
                #pragma unroll
                for (int j = 0; j < 2; ++j)
                    acc[i][2 + j] = __builtin_amdgcn_mfma_f32_16x16x32_bf16(
                        aA[ks][i], bQ1[ks][j], acc[i][2 + j], 0, 0, 0);
        __builtin_amdgcn_s_setprio(0);
        BAR();

        // ===== phase 2: (mh=1, nq=1) — reads 8 (A-half 1) =====
        #pragma unroll
        for (int i = 0; i < 4; ++i) {
            aA[0][i] = *(const bf16x8*)&As[cur][abase[4 + i] + bo0];
            aA[1][i] = *(const bf16x8*)&As[cur][abase[4 + i] + bo1];
        }
        BAR();
        __builtin_amdgcn_s_setprio(1);
        #pragma unroll
        for (int ks = 0; ks < 2; ++ks)
            #pragma unroll
            for (int i = 0; i < 4; ++i)
                #pragma unroll
                for (int j = 0; j < 2; ++j)
                    acc[4 + i][2 + j] = __builtin_amdgcn_mfma_f32_16x16x32_bf16(
                        aA[ks][i], bQ1[ks][j], acc[4 + i][2 + j], 0, 0, 0);
        __builtin_amdgcn_s_setprio(0);
        BAR();

        // ===== phase 3: (mh=1, nq=0) — no reads; drain prefetch =====
        asm volatile("s_waitcnt vmcnt(0)" ::: "memory");
        BAR();
        __builtin_amdgcn_s_setprio(1);
        #pragma unroll
        for (int ks = 0; ks < 2; ++ks)
            #pragma unroll
            for (int i = 0; i < 4; ++i)
                #pragma unroll
                for (int j = 0; j < 2; ++j)
                    acc[4 + i][j] = __builtin_amdgcn_mfma_f32_16x16x32_bf16(
                        aA[ks][i], bQ0[ks][j], acc[4 + i][j], 0, 0, 0);
        __builtin_amdgcn_s_setprio(0);
        BAR();
    }

    // ---- epilogue: out = 2*acc - xsq[row] - ysq[col] ----
    // C/D layout (16x16): col = lane&15, row = (lane>>4)*4 + reg
    #pragma unroll
    for (int i = 0; i < 8; ++i) {
        int r0 = tm * BM + wm * 128 + i * 16 + hi * 4;
        #pragma unroll
        for (int n = 0; n < 4; ++n) {
            int c = tn * BN + wn * 64 + n * 16 + l15;
            float ysv = ysq[c];
            #pragma unroll
            for (int r = 0; r < 4; ++r) {
                out[(size_t)(r0 + r) * N + c] =
                    2.0f * acc[i][n][r] - xsq[r0 + r] - ysv;
            }
        }
    }
}

// ---------------- fallback (only if ws too small): exact f32 --------------
__global__ __launch_bounds__(256) void fallback_l2(
    const float* __restrict__ x, const float* __restrict__ y,
    float* __restrict__ out, int M, int N)
{
    int tx = threadIdx.x & 15, ty = threadIdx.x >> 4;
    int row = blockIdx.y * 16 + ty;
    int col = blockIdx.x * 16 + tx;
    __shared__ float xs[16][17], ys[16][17];
    float s = 0.f;
    for (int k0 = 0; k0 < KDIM; k0 += 16) {
        xs[ty][tx] = x[(size_t)row * KDIM + k0 + tx];
        ys[ty][tx] = y[(size_t)(blockIdx.x * 16 + ty) * KDIM + k0 + tx];
        __syncthreads();
        #pragma unroll
        for (int kk = 0; kk < 16; ++kk) {
            float d = xs[ty][kk] - ys[tx][kk];
            s += d * d;
        }
        __syncthreads();
    }
    out[(size_t)row * N + col] = -s;
}

extern "C" void kernel_launch(void* const* d_in, const int* in_sizes, int n_in,
                              void* d_out, int out_size, void* d_ws, size_t ws_size,
                              hipStream_t stream) {
    const float* x = (const float*)d_in[0];
    const float* y = (const float*)d_in[1];
    float* out = (float*)d_out;
    const int M = in_sizes[0] / KDIM;   // 4096
    const int N = in_sizes[1] / KDIM;   // 8192

    size_t need = (size_t)(M + N) * KDIM * sizeof(short)
                + (size_t)(M + N) * sizeof(float) + 256;
    if (ws_size >= need) {
        char* w = (char*)d_ws;
        short* xb  = (short*)w;
        short* yb  = xb + (size_t)M * KDIM;
        float* xsq = (float*)(yb + (size_t)N * KDIM);
        float* ysq = xsq + M;

        prep_kernel<<<M + N, 256, 0, stream>>>(x, y, xb, yb, xsq, ysq, M, N);
        int grid = (M / BM) * (N / BN);   // 16*32 = 512 (divisible by 8)
        gemm_l2<<<grid, 512, 0, stream>>>(xb, yb, xsq, ysq, out, M, N);
    } else {
        dim3 g(N / 16, M / 16);
        fallback_l2<<<g, 256, 0, stream>>>(x, y, out, M, N);
    }
}

// Round 4
// 94.542 us; speedup vs baseline: 1.0767x; 1.0767x over previous
//
#include <hip/hip_runtime.h>
#include <hip/hip_bf16.h>

// out[b,n] = 2*x.y - ||x_b||^2 - ||y_n||^2
// x: [M=4096, K=1024] f32   y: [N=8192, K=1024] f32   out: [M, N] f32
//
// Round 4: m201-geometry pipeline at k-half granularity.
// - 4 LDS slots (32 KiB each): A[256][32] + B[256][32] bf16, 64 B rows
// - per k-half: 2 phases x {ds_reads(8/4); 2 gld_lds; BAR; lgkm0; 16 MFMA; BAR}
// - counted vmcnt(4) once per half (1 half stays in flight); vmcnt(0) only at tail
// - LDS swizzle: physical 16B-block = hi ^ ((row>>1)&3), via pre-swizzled global src
// - 8x8-region XCD swizzle for L2/L3 locality

typedef __attribute__((ext_vector_type(8))) short bf16x8;
typedef __attribute__((ext_vector_type(4))) float f32x4;

#define BM 256
#define BN 256
#define KDIM 1024
#define NHALF (KDIM / 32)      // 32 k-halves
#define SLOT_SH 16384          // shorts per slot (32 KiB)
#define BOFF 8192              // B offset within slot (shorts)

__device__ __forceinline__ short f2bf(float f) {
    __hip_bfloat16 h = __float2bfloat16(f);
    return *reinterpret_cast<short*>(&h);
}

__device__ __forceinline__ void gld16(const short* g, short* l) {
    __builtin_amdgcn_global_load_lds(
        (const __attribute__((address_space(1))) unsigned int*)g,
        (__attribute__((address_space(3))) unsigned int*)l,
        16, 0, 0);
}

#define BAR()   asm volatile("s_barrier" ::: "memory")
#define LGKM0() asm volatile("s_waitcnt lgkmcnt(0)" ::: "memory")

// ---------------- prep: f32 -> bf16 + row squared-norms -------------------
__global__ __launch_bounds__(256) void prep_kernel(
    const float* __restrict__ x, const float* __restrict__ y,
    short* __restrict__ xb, short* __restrict__ yb,
    float* __restrict__ xsq, float* __restrict__ ysq, int M, int N)
{
    int row = blockIdx.x;
    const float* src;
    short* dst;
    float* nrm;
    if (row < M) {
        src = x + (size_t)row * KDIM;
        dst = xb + (size_t)row * KDIM;
        nrm = xsq + row;
    } else {
        int r = row - M;
        src = y + (size_t)r * KDIM;
        dst = yb + (size_t)r * KDIM;
        nrm = ysq + r;
    }
    int t = threadIdx.x;                       // 256 threads, 4 floats each
    float4 v = ((const float4*)src)[t];
    float s = v.x * v.x + v.y * v.y + v.z * v.z + v.w * v.w;
    short4 o;
    o.x = f2bf(v.x); o.y = f2bf(v.y); o.z = f2bf(v.z); o.w = f2bf(v.w);
    ((short4*)dst)[t] = o;

    #pragma unroll
    for (int off = 32; off > 0; off >>= 1) s += __shfl_down(s, off, 64);
    __shared__ float red[4];
    if ((t & 63) == 0) red[t >> 6] = s;
    __syncthreads();
    if (t == 0) *nrm = red[0] + red[1] + red[2] + red[3];
}

// ---------------- main 256x256 k-half-pipelined bf16 MFMA GEMM ------------
__global__ __launch_bounds__(512, 2) void gemm_l2(
    const short* __restrict__ xb, const short* __restrict__ yb,
    const float* __restrict__ xsq, const float* __restrict__ ysq,
    float* __restrict__ out, int M, int N)
{
    __shared__ __align__(16) short lds[4 * SLOT_SH];   // 128 KiB, 4 slots

    const int ntm = M / BM;             // 16
    const int ntn = N / BN;             // 32
    const int bid = blockIdx.x;
    int tm, tn;
    if (ntm == 16 && ntn == 32) {
        // 8x8-region XCD swizzle: each XCD owns an 8x8 block of tiles
        int xcd = bid & 7, k = bid >> 3;            // k = 0..63
        tm = (xcd >> 2) * 8 + (k >> 3);
        tn = (xcd & 3) * 8 + (k & 7);
    } else {
        tm = bid / ntn;
        tn = bid % ntn;
    }

    const int tid  = threadIdx.x;       // 512 threads = 8 waves
    const int wid  = tid >> 6;
    const int lane = tid & 63;
    const int wm   = wid >> 2;          // 0..1  (wave tile: 128 x 64)
    const int wn   = wid & 3;           // 0..3
    const int l15  = lane & 15;
    const int hi   = lane >> 4;         // 0..3

    // ---- staging: per half, 2 A-loads + 2 B-loads per thread ----
    // gld_lds writes LINEAR (base + lane*16B); swizzle applied by permuting
    // the GLOBAL source 16B-block: sb = pb ^ ((row>>1)&3), pb = lane&3.
    const int sb = (lane & 3) ^ ((lane >> 3) & 3);
    const short* aS[2];
    const short* bS[2];
    int asd[2], bsd[2];
    #pragma unroll
    for (int c = 0; c < 2; ++c) {
        int row = c * 128 + wid * 16 + (lane >> 2);     // 0..255
        aS[c] = xb + (size_t)(tm * BM + row) * KDIM + sb * 8;
        bS[c] = yb + (size_t)(tn * BN + row) * KDIM + sb * 8;
        asd[c] = (c * 128 + wid * 16) * 32 + lane * 8;  // == row*32 + (lane&3)*8
        bsd[c] = asd[c] + BOFF;
    }

    // ---- fragment read offsets (shorts); physical block = hi ^ ((l15>>1)&3)
    const int xk = (hi ^ ((l15 >> 1) & 3)) * 8;
    int aro[8], bro[4];
    #pragma unroll
    for (int mi = 0; mi < 8; ++mi)
        aro[mi] = (wm * 128 + mi * 16 + l15) * 32 + xk;
    #pragma unroll
    for (int n = 0; n < 4; ++n)
        bro[n] = (wn * 64 + n * 16 + l15) * 32 + xk + BOFF;

    f32x4 acc[8][4] = {};

    // ---- prologue: stage halves 0,1 (8 loads); drain half 0 ----
    #pragma unroll
    for (int h = 0; h < 2; ++h) {
        short* s0 = &lds[h * SLOT_SH];
        gld16(aS[0] + h * 32, s0 + asd[0]);
        gld16(aS[1] + h * 32, s0 + asd[1]);
        gld16(bS[0] + h * 32, s0 + bsd[0]);
        gld16(bS[1] + h * 32, s0 + bsd[1]);
    }
    asm volatile("s_waitcnt vmcnt(4)" ::: "memory");
    BAR();

    for (int s = 0; s < NHALF; ++s) {
        const short* sl = &lds[(s & 3) * SLOT_SH];
        const int h2 = s + 2;
        short* s2 = &lds[(h2 & 3) * SLOT_SH];

        bf16x8 aF[4], bF[4];

        // ===== phase 0: A-half0 x all B (8 reads, stage 2 A-loads) =====
        #pragma unroll
        for (int n = 0; n < 4; ++n) bF[n] = *(const bf16x8*)&sl[bro[n]];
        #pragma unroll
        for (int i = 0; i < 4; ++i) aF[i] = *(const bf16x8*)&sl[aro[i]];
        if (h2 < NHALF) {
            gld16(aS[0] + h2 * 32, s2 + asd[0]);
            gld16(aS[1] + h2 * 32, s2 + asd[1]);
        }
        BAR();
        LGKM0();
        __builtin_amdgcn_sched_barrier(0);
        __builtin_amdgcn_s_setprio(1);
        #pragma unroll
        for (int i = 0; i < 4; ++i)
            #pragma unroll
            for (int n = 0; n < 4; ++n)
                acc[i][n] = __builtin_amdgcn_mfma_f32_16x16x32_bf16(
                    aF[i], bF[n], acc[i][n], 0, 0, 0);
        __builtin_amdgcn_s_setprio(0);
        BAR();

        // ===== phase 1: A-half1 x all B (4 reads, stage 2 B-loads) =====
        #pragma unroll
        for (int i = 0; i < 4; ++i) aF[i] = *(const bf16x8*)&sl[aro[4 + i]];
        if (h2 < NHALF) {
            gld16(bS[0] + h2 * 32, s2 + bsd[0]);
            gld16(bS[1] + h2 * 32, s2 + bsd[1]);
        }
        // counted drain: half s+1 must be resident before next iteration
        if (s < NHALF - 2) {
            asm volatile("s_waitcnt vmcnt(4)" ::: "memory");
        } else if (s == NHALF - 2) {
            asm volatile("s_waitcnt vmcnt(0)" ::: "memory");
        }
        BAR();
        LGKM0();
        __builtin_amdgcn_sched_barrier(0);
        __builtin_amdgcn_s_setprio(1);
        #pragma unroll
        for (int i = 0; i < 4; ++i)
            #pragma unroll
            for (int n = 0; n < 4; ++n)
                acc[4 + i][n] = __builtin_amdgcn_mfma_f32_16x16x32_bf16(
                    aF[i], bF[n], acc[4 + i][n], 0, 0, 0);
        __builtin_amdgcn_s_setprio(0);
        BAR();
    }

    // ---- epilogue: out = 2*acc - xsq[row] - ysq[col] ----
    // C/D layout (16x16): col = lane&15, row = (lane>>4)*4 + reg
    #pragma unroll
    for (int i = 0; i < 8; ++i) {
        int r0 = tm * BM + wm * 128 + i * 16 + hi * 4;
        #pragma unroll
        for (int n = 0; n < 4; ++n) {
            int c = tn * BN + wn * 64 + n * 16 + l15;
            float ysv = ysq[c];
            #pragma unroll
            for (int r = 0; r < 4; ++r) {
                out[(size_t)(r0 + r) * N + c] =
                    2.0f * acc[i][n][r] - xsq[r0 + r] - ysv;
            }
        }
    }
}

// ---------------- fallback (only if ws too small): exact f32 --------------
__global__ __launch_bounds__(256) void fallback_l2(
    const float* __restrict__ x, const float* __restrict__ y,
    float* __restrict__ out, int M, int N)
{
    int tx = threadIdx.x & 15, ty = threadIdx.x >> 4;
    int row = blockIdx.y * 16 + ty;
    int col = blockIdx.x * 16 + tx;
    __shared__ float xs[16][17], ys[16][17];
    float s = 0.f;
    for (int k0 = 0; k0 < KDIM; k0 += 16) {
        xs[ty][tx] = x[(size_t)row * KDIM + k0 + tx];
        ys[ty][tx] = y[(size_t)(blockIdx.x * 16 + ty) * KDIM + k0 + tx];
        __syncthreads();
        #pragma unroll
        for (int kk = 0; kk < 16; ++kk) {
            float d = xs[ty][kk] - ys[tx][kk];
            s += d * d;
        }
        __syncthreads();
    }
    out[(size_t)row * N + col] = -s;
}

extern "C" void kernel_launch(void* const* d_in, const int* in_sizes, int n_in,
                              void* d_out, int out_size, void* d_ws, size_t ws_size,
                              hipStream_t stream) {
    const float* x = (const float*)d_in[0];
    const float* y = (const float*)d_in[1];
    float* out = (float*)d_out;
    const int M = in_sizes[0] / KDIM;   // 4096
    const int N = in_sizes[1] / KDIM;   // 8192

    size_t need = (size_t)(M + N) * KDIM * sizeof(short)
                + (size_t)(M + N) * sizeof(float) + 256;
    if (ws_size >= need) {
        char* w = (char*)d_ws;
        short* xb  = (short*)w;
        short* yb  = xb + (size_t)M * KDIM;
        float* xsq = (float*)(yb + (size_t)N * KDIM);
        float* ysq = xsq + M;

        prep_kernel<<<M + N, 256, 0, stream>>>(x, y, xb, yb, xsq, ysq, M, N);
        int grid = (M / BM) * (N / BN);   // 16*32 = 512
        gemm_l2<<<grid, 512, 0, stream>>>(xb, yb, xsq, ysq, out, M, N);
    } else {
        dim3 g(N / 16, M / 16);
        fallback_l2<<<g, 256, 0, stream>>>(x, y, out, M, N);
    }
}